// Round 2
// baseline (145.840 us; speedup 1.0000x reference)
//
#include <hip/hip_runtime.h>
#include <math.h>

// Problem constants (fixed by setup_inputs): B=4, N=2048, C=32
#define NB 4
#define NA 2048
#define NC 32
#define JT 128                 // j-atoms staged in LDS per block
#define IT 256                 // i-atoms per block (= block size)
#define NJ (NA / JT)           // 16
#define NI (NA / IT)           // 8
#define NBLOCKS (NB * NI * NJ) // 512

static constexpr float CONV001 = 3.3207156f;   // 332.07156 * 0.01

// ws layout (floats): ws[0..3] = per-batch accumulator (2*E_self + E_pair_partial)
//                     ws[4]    = block-completion counter (as unsigned)
// kernel_launch zeroes the first 32 B each call.

__global__ void __launch_bounds__(IT)
fused_kernel(const float* __restrict__ X,
             const float* __restrict__ embs,
             const float* __restrict__ qs,
             const float* __restrict__ born,
             const float* __restrict__ die,
             const float* __restrict__ sf,
             float* __restrict__ ws,
             float* __restrict__ out) {
    const int b  = blockIdx.z;
    const int i  = blockIdx.y * IT + threadIdx.x;
    const int j0 = blockIdx.x * JT;
    const int t  = threadIdx.x;

    const float* Xb = X + (size_t)b * NA * 3;
    const float* Eb = embs + (size_t)b * NA * NC;

    __shared__ float4 jd[JT];          // {x, y, z, s_j} per staged j-atom

    // --- stage j-tile: threads 0..127 each compute one s_j dot + position ---
    if (t < JT) {
        int j = j0 + t;
        const float4* e4 = (const float4*)(Eb + (size_t)j * NC);
        float sj = 0.f;
        #pragma unroll
        for (int c = 0; c < NC / 4; ++c) {
            float4 ev = e4[c];
            sj += ev.x * sf[NC + 4 * c + 0] + ev.y * sf[NC + 4 * c + 1]
                + ev.z * sf[NC + 4 * c + 2] + ev.w * sf[NC + 4 * c + 3];
        }
        jd[t] = make_float4(Xb[j * 3 + 0], Xb[j * 3 + 1], Xb[j * 3 + 2], sj);
    }

    // --- per-i quantities (each thread owns one i) ---
    const float4* ei4 = (const float4*)(Eb + (size_t)i * NC);
    float si = 0.f;
    #pragma unroll
    for (int c = 0; c < NC / 4; ++c) {
        float4 ev = ei4[c];
        si += ev.x * sf[4 * c + 0] + ev.y * sf[4 * c + 1]
            + ev.z * sf[4 * c + 2] + ev.w * sf[4 * c + 3];
    }
    float xi = Xb[i * 3 + 0];
    float yi = Xb[i * 3 + 1];
    float zi = Xb[i * 3 + 2];

    float acc = 0.f;
    // E_self folded in once per i (weight 2: finalize multiplies by 0.5)
    if (blockIdx.x == 0) {
        float ad = 0.f, R = 0.f;
        #pragma unroll
        for (int c = 0; c < NC / 4; ++c) {
            float4 ev = ei4[c];
            ad += ev.x * die[4 * c + 0] + ev.y * die[4 * c + 1]
                + ev.z * die[4 * c + 2] + ev.w * die[4 * c + 3];
            R  += ev.x * born[4 * c + 0] + ev.y * born[4 * c + 1]
                + ev.z * born[4 * c + 2] + ev.w * born[4 * c + 3];
        }
        ad += 1e-6f;
        R  += 1.0f;
        float eself = -(1.0f - __builtin_amdgcn_rcpf(ad)) * qs[b * NA + i]
                      * __builtin_amdgcn_rcpf(R + 1e-6f);
        acc = 2.0f * eself;
    }
    __syncthreads();

    // --- pair loop over staged j-tile ---
    // E_pair = (si+sj)/(D+eps) + wd*D/(D+eps) ~= rsqrt(d2)*(si+sj) + wd,
    // the wd term is accounted in closed form (wd*N^2) at finalize.
    #pragma unroll 8
    for (int jj = 0; jj < JT; ++jj) {
        float4 v = jd[jj];
        float dx = v.x - xi;
        float dy = v.y - yi;
        float dz = v.z - zi;
        float d2 = fmaf(dx, dx, fmaf(dy, dy, fmaf(dz, dz, 3e-6f)));
        acc = fmaf(__builtin_amdgcn_rsqf(d2), si + v.w, acc);
    }

    // --- block reduction (wave-64 butterfly, then cross-wave) ---
    #pragma unroll
    for (int off = 32; off > 0; off >>= 1)
        acc += __shfl_down(acc, off, 64);
    __shared__ float wsum[IT / 64];
    int lane = t & 63;
    int w = t >> 6;
    if (lane == 0) wsum[w] = acc;
    __syncthreads();
    if (t == 0) {
        float bs = wsum[0] + wsum[1] + wsum[2] + wsum[3];
        atomicAdd(&ws[b], bs);
    }

    // --- last-block-done finalize ---
    __threadfence();
    __shared__ bool amLast;
    if (t == 0) {
        unsigned old = atomicAdd((unsigned*)&ws[NB], 1u);
        amLast = (old == NBLOCKS - 1);
    }
    __syncthreads();
    if (amLast && t < NB) {
        float accb = __hip_atomic_load(&ws[t], __ATOMIC_RELAXED,
                                       __HIP_MEMORY_SCOPE_AGENT);
        float wd = sf[2 * NC];
        float v = CONV001 * 0.5f * (accb + wd * (float)NA * (float)NA);
        out[t] = isnan(v) ? 1e-6f : v;
    }
}

extern "C" void kernel_launch(void* const* d_in, const int* in_sizes, int n_in,
                              void* d_out, int out_size, void* d_ws, size_t ws_size,
                              hipStream_t stream) {
    const float* X    = (const float*)d_in[0];
    const float* embs = (const float*)d_in[1];
    const float* qs   = (const float*)d_in[2];
    // d_in[3] = paired_mask (unused by reference math)
    const float* born = (const float*)d_in[4];
    const float* die  = (const float*)d_in[5];
    const float* sf   = (const float*)d_in[6];
    float* ws  = (float*)d_ws;
    float* out = (float*)d_out;

    // zero 4 accumulators + completion counter (ws is poisoned each call)
    hipMemsetAsync(ws, 0, 8 * sizeof(float), stream);

    fused_kernel<<<dim3(NJ, NI, NB), IT, 0, stream>>>(X, embs, qs, born, die,
                                                      sf, ws, out);
}

// Round 3
// 119.893 us; speedup vs baseline: 1.2164x; 1.2164x over previous
//
#include <hip/hip_runtime.h>
#include <math.h>

// Problem constants (fixed by setup_inputs): B=4, N=2048, C=32
#define NB 4
#define NA 2048
#define NC 32
#define IT 256                  // threads per block
#define UI 2                    // i-atoms per thread (register tile / ILP)
#define ITILE (IT * UI)         // 512 i per block
#define NS 64                   // j-splits (parallelism)
#define JT (NA / NS)            // 32 j per block
// grid = (NS, NA/ITILE, NB) = (64, 4, 4) = 1024 blocks = 4096 waves = 16/CU

static constexpr float CONV001 = 3.3207156f;   // 332.07156 * 0.01

// ws[0..3] = per-batch accumulator: 2*E_self_sum + pair_partial

__global__ void __launch_bounds__(IT)
pair_kernel(const float* __restrict__ X,
            const float* __restrict__ embs,
            const float* __restrict__ qs,
            const float* __restrict__ born,
            const float* __restrict__ die,
            const float* __restrict__ sf,
            float* __restrict__ ws) {
    const int b  = blockIdx.z;
    const int t  = threadIdx.x;
    const int i0 = blockIdx.y * ITILE;
    const int j0 = blockIdx.x * JT;

    const float* Xb = X + (size_t)b * NA * 3;
    const float* Eb = embs + (size_t)b * NA * NC;

    __shared__ float4 jd[JT];   // {x, y, z, s_j}

    // --- stage j-tile (threads 0..JT-1) ---
    if (t < JT) {
        int j = j0 + t;
        const float4* e4 = (const float4*)(Eb + (size_t)j * NC);
        float sj = 0.f;
        #pragma unroll
        for (int c = 0; c < NC / 4; ++c) {
            float4 ev = e4[c];
            sj = fmaf(ev.x, sf[NC + 4 * c + 0],
                 fmaf(ev.y, sf[NC + 4 * c + 1],
                 fmaf(ev.z, sf[NC + 4 * c + 2],
                 fmaf(ev.w, sf[NC + 4 * c + 3], sj))));
        }
        jd[t] = make_float4(Xb[j * 3 + 0], Xb[j * 3 + 1], Xb[j * 3 + 2], sj);
    }

    // --- per-thread i data (UI independent atoms) ---
    float xi[UI], yi[UI], zi[UI], si[UI], acc[UI];
    #pragma unroll
    for (int u = 0; u < UI; ++u) {
        int i = i0 + u * IT + t;
        const float4* e4 = (const float4*)(Eb + (size_t)i * NC);
        float s = 0.f;
        #pragma unroll
        for (int c = 0; c < NC / 4; ++c) {
            float4 ev = e4[c];
            s = fmaf(ev.x, sf[4 * c + 0],
                fmaf(ev.y, sf[4 * c + 1],
                fmaf(ev.z, sf[4 * c + 2],
                fmaf(ev.w, sf[4 * c + 3], s))));
        }
        si[u] = s;
        xi[u] = Xb[i * 3 + 0];
        yi[u] = Xb[i * 3 + 1];
        zi[u] = Xb[i * 3 + 2];
        acc[u] = 0.f;

        // E_self folded in once per i (weight 2: finalize multiplies by 0.5)
        if (blockIdx.x == 0) {
            float ad = 0.f, R = 0.f;
            #pragma unroll
            for (int c = 0; c < NC / 4; ++c) {
                float4 ev = e4[c];
                ad = fmaf(ev.x, die[4 * c + 0],
                     fmaf(ev.y, die[4 * c + 1],
                     fmaf(ev.z, die[4 * c + 2],
                     fmaf(ev.w, die[4 * c + 3], ad))));
                R  = fmaf(ev.x, born[4 * c + 0],
                     fmaf(ev.y, born[4 * c + 1],
                     fmaf(ev.z, born[4 * c + 2],
                     fmaf(ev.w, born[4 * c + 3], R))));
            }
            ad += 1e-6f;
            R  += 1.0f;
            float eself = -(1.0f - __builtin_amdgcn_rcpf(ad)) * qs[b * NA + i]
                          * __builtin_amdgcn_rcpf(R + 1e-6f);
            acc[u] = 2.0f * eself;
        }
    }
    __syncthreads();

    // --- pair loop: E_pair ~= rsqrt(d2)*(si+sj) + wd  (wd*N^2 closed-form
    //     at finalize). UI independent chains per LDS read; unroll 4 batches
    //     ds_read_b128s ahead of the VALU block.
    #pragma unroll 4
    for (int jj = 0; jj < JT; ++jj) {
        float4 v = jd[jj];
        #pragma unroll
        for (int u = 0; u < UI; ++u) {
            float dx = v.x - xi[u];
            float dy = v.y - yi[u];
            float dz = v.z - zi[u];
            float d2 = fmaf(dx, dx, fmaf(dy, dy, fmaf(dz, dz, 3e-6f)));
            acc[u] = fmaf(__builtin_amdgcn_rsqf(d2), si[u] + v.w, acc[u]);
        }
    }

    // --- block reduction ---
    float a = 0.f;
    #pragma unroll
    for (int u = 0; u < UI; ++u) a += acc[u];
    #pragma unroll
    for (int off = 32; off > 0; off >>= 1)
        a += __shfl_down(a, off, 64);
    __shared__ float wsum[IT / 64];
    int lane = t & 63;
    int w = t >> 6;
    if (lane == 0) wsum[w] = a;
    __syncthreads();
    if (t == 0) {
        float bs = wsum[0] + wsum[1] + wsum[2] + wsum[3];
        atomicAdd(&ws[b], bs);   // f32, no return -> fire-and-forget
    }
}

__global__ void finalize_kernel(const float* __restrict__ ws,
                                const float* __restrict__ sf,
                                float* __restrict__ out) {
    int b = threadIdx.x;
    if (b < NB) {
        float wd = sf[2 * NC];
        float v = CONV001 * 0.5f * (ws[b] + wd * (float)NA * (float)NA);
        out[b] = isnan(v) ? 1e-6f : v;
    }
}

extern "C" void kernel_launch(void* const* d_in, const int* in_sizes, int n_in,
                              void* d_out, int out_size, void* d_ws, size_t ws_size,
                              hipStream_t stream) {
    const float* X    = (const float*)d_in[0];
    const float* embs = (const float*)d_in[1];
    const float* qs   = (const float*)d_in[2];
    // d_in[3] = paired_mask (unused by reference math)
    const float* born = (const float*)d_in[4];
    const float* die  = (const float*)d_in[5];
    const float* sf   = (const float*)d_in[6];
    float* ws  = (float*)d_ws;
    float* out = (float*)d_out;

    // zero the 4 per-batch accumulators (ws is poisoned each call)
    hipMemsetAsync(ws, 0, NB * sizeof(float), stream);

    pair_kernel<<<dim3(NS, NA / ITILE, NB), IT, 0, stream>>>(X, embs, qs,
                                                             born, die, sf, ws);
    finalize_kernel<<<1, 64, 0, stream>>>(ws, sf, out);
}

// Round 4
// 110.648 us; speedup vs baseline: 1.3180x; 1.0836x over previous
//
#include <hip/hip_runtime.h>
#include <math.h>

// Problem constants (fixed by setup_inputs): B=4, N=2048, C=32
#define NB 4
#define NA 2048
#define NC 32
#define IT 256                  // threads per block
#define UI 2                    // i-atoms per thread (register tile / ILP)
#define ITILE (IT * UI)         // 512 i per block
#define NS 64                   // j-splits (parallelism)
#define JT (NA / NS)            // 32 j per block
#define NI (NA / ITILE)         // 4
#define SLOTS_PER_B (NI * NS)   // 256 partial-sum slots per batch
// grid = (NS, NI, NB) = (64, 4, 4) = 1024 blocks = 4096 waves = 16/CU

static constexpr float CONV001 = 3.3207156f;   // 332.07156 * 0.01

// ws[0 .. NB*SLOTS_PER_B) : per-block partial sums (every slot fully
// overwritten each call -> no zeroing needed despite 0xAA poison).

__global__ void __launch_bounds__(IT)
pair_kernel(const float* __restrict__ X,
            const float* __restrict__ embs,
            const float* __restrict__ qs,
            const float* __restrict__ born,
            const float* __restrict__ die,
            const float* __restrict__ sf,
            float* __restrict__ ws) {
    const int b  = blockIdx.z;
    const int t  = threadIdx.x;
    const int i0 = blockIdx.y * ITILE;
    const int j0 = blockIdx.x * JT;

    const float* Xb = X + (size_t)b * NA * 3;
    const float* Eb = embs + (size_t)b * NA * NC;

    __shared__ float4 jd[JT];   // {x, y, z, s_j}

    // --- stage j-tile (threads 0..JT-1) ---
    if (t < JT) {
        int j = j0 + t;
        const float4* e4 = (const float4*)(Eb + (size_t)j * NC);
        float sj = 0.f;
        #pragma unroll
        for (int c = 0; c < NC / 4; ++c) {
            float4 ev = e4[c];
            sj = fmaf(ev.x, sf[NC + 4 * c + 0],
                 fmaf(ev.y, sf[NC + 4 * c + 1],
                 fmaf(ev.z, sf[NC + 4 * c + 2],
                 fmaf(ev.w, sf[NC + 4 * c + 3], sj))));
        }
        jd[t] = make_float4(Xb[j * 3 + 0], Xb[j * 3 + 1], Xb[j * 3 + 2], sj);
    }

    // --- per-thread i data (UI independent atoms) ---
    float xi[UI], yi[UI], zi[UI], si[UI], acc[UI];
    #pragma unroll
    for (int u = 0; u < UI; ++u) {
        int i = i0 + u * IT + t;
        const float4* e4 = (const float4*)(Eb + (size_t)i * NC);
        float s = 0.f;
        #pragma unroll
        for (int c = 0; c < NC / 4; ++c) {
            float4 ev = e4[c];
            s = fmaf(ev.x, sf[4 * c + 0],
                fmaf(ev.y, sf[4 * c + 1],
                fmaf(ev.z, sf[4 * c + 2],
                fmaf(ev.w, sf[4 * c + 3], s))));
        }
        si[u] = s;
        xi[u] = Xb[i * 3 + 0];
        yi[u] = Xb[i * 3 + 1];
        zi[u] = Xb[i * 3 + 2];
        acc[u] = 0.f;

        // E_self folded in once per i (weight 2: finalize multiplies by 0.5)
        if (blockIdx.x == 0) {
            float ad = 0.f, R = 0.f;
            #pragma unroll
            for (int c = 0; c < NC / 4; ++c) {
                float4 ev = e4[c];
                ad = fmaf(ev.x, die[4 * c + 0],
                     fmaf(ev.y, die[4 * c + 1],
                     fmaf(ev.z, die[4 * c + 2],
                     fmaf(ev.w, die[4 * c + 3], ad))));
                R  = fmaf(ev.x, born[4 * c + 0],
                     fmaf(ev.y, born[4 * c + 1],
                     fmaf(ev.z, born[4 * c + 2],
                     fmaf(ev.w, born[4 * c + 3], R))));
            }
            ad += 1e-6f;
            R  += 1.0f;
            float eself = -(1.0f - __builtin_amdgcn_rcpf(ad)) * qs[b * NA + i]
                          * __builtin_amdgcn_rcpf(R + 1e-6f);
            acc[u] = 2.0f * eself;
        }
    }
    __syncthreads();

    // --- pair loop: E_pair ~= rsqrt(d2)*(si+sj) + wd  (wd*N^2 accounted in
    //     closed form at finalize). UI independent chains per LDS read.
    #pragma unroll 4
    for (int jj = 0; jj < JT; ++jj) {
        float4 v = jd[jj];
        #pragma unroll
        for (int u = 0; u < UI; ++u) {
            float dx = v.x - xi[u];
            float dy = v.y - yi[u];
            float dz = v.z - zi[u];
            float d2 = fmaf(dx, dx, fmaf(dy, dy, fmaf(dz, dz, 3e-6f)));
            acc[u] = fmaf(__builtin_amdgcn_rsqf(d2), si[u] + v.w, acc[u]);
        }
    }

    // --- block reduction -> private slot (no atomics, no pre-zero) ---
    float a = 0.f;
    #pragma unroll
    for (int u = 0; u < UI; ++u) a += acc[u];
    #pragma unroll
    for (int off = 32; off > 0; off >>= 1)
        a += __shfl_down(a, off, 64);
    __shared__ float wsum[IT / 64];
    int lane = t & 63;
    int w = t >> 6;
    if (lane == 0) wsum[w] = a;
    __syncthreads();
    if (t == 0) {
        int slot = (b * NI + blockIdx.y) * NS + blockIdx.x;
        ws[slot] = wsum[0] + wsum[1] + wsum[2] + wsum[3];
    }
}

// One block of 1024 threads: 16 waves; batch b owns waves 4b..4b+3.
__global__ void __launch_bounds__(1024)
finalize_kernel(const float* __restrict__ ws,
                const float* __restrict__ sf,
                float* __restrict__ out) {
    int t = threadIdx.x;
    float v = ws[t];
    #pragma unroll
    for (int off = 32; off > 0; off >>= 1)
        v += __shfl_down(v, off, 64);
    __shared__ float wsum[16];
    if ((t & 63) == 0) wsum[t >> 6] = v;
    __syncthreads();
    if (t < NB) {
        float accb = wsum[4 * t] + wsum[4 * t + 1]
                   + wsum[4 * t + 2] + wsum[4 * t + 3];
        float wd = sf[2 * NC];
        float r = CONV001 * 0.5f * (accb + wd * (float)NA * (float)NA);
        out[t] = isnan(r) ? 1e-6f : r;
    }
}

extern "C" void kernel_launch(void* const* d_in, const int* in_sizes, int n_in,
                              void* d_out, int out_size, void* d_ws, size_t ws_size,
                              hipStream_t stream) {
    const float* X    = (const float*)d_in[0];
    const float* embs = (const float*)d_in[1];
    const float* qs   = (const float*)d_in[2];
    // d_in[3] = paired_mask (unused by reference math)
    const float* born = (const float*)d_in[4];
    const float* die  = (const float*)d_in[5];
    const float* sf   = (const float*)d_in[6];
    float* ws  = (float*)d_ws;
    float* out = (float*)d_out;

    pair_kernel<<<dim3(NS, NI, NB), IT, 0, stream>>>(X, embs, qs,
                                                     born, die, sf, ws);
    finalize_kernel<<<1, 1024, 0, stream>>>(ws, sf, out);
}

// Round 5
// 108.140 us; speedup vs baseline: 1.3486x; 1.0232x over previous
//
#include <hip/hip_runtime.h>
#include <math.h>

// Problem constants (fixed by setup_inputs): B=4, N=2048, C=32
#define NB 4
#define NA 2048
#define NC 32
#define NATOM (NB * NA)         // 8192
#define IT 256                  // threads per block (pair kernel)
#define UI 2                    // i-atoms per thread (ILP)
#define ITILE (IT * UI)         // 512 i per block
#define NS 64                   // j-splits
#define JT (NA / NS)            // 32 j per block
#define NI (NA / ITILE)         // 4
// pair grid = (NS, NI, NB) = 1024 blocks = 4096 waves = 16/CU

static constexpr float CONV001 = 3.3207156f;   // 332.07156 * 0.01

// ws layout (floats) — every slot fully overwritten each call (poison-safe):
//   [0, 32768)        Pi[a] = {x,y,z,s_i}  (8192 float4)
//   [32768, 65536)    Pj[a] = {x,y,z,s_j}  (8192 float4)
//   [65536, 66560)    pair partial slots (1024)
//   [66560, 66592)    self partial slots (32; 8 per batch)
#define WS_PI   0
#define WS_PJ   32768
#define WS_PAIR 65536
#define WS_SELF 66560

// Pass 1: per-atom scalars + packed position/scalar arrays + E_self partials.
// grid = 32 blocks x 256 (block k covers atoms [256k, 256k+256), batch k/8).
__global__ void __launch_bounds__(256)
atom_kernel(const float* __restrict__ X,
            const float* __restrict__ embs,
            const float* __restrict__ qs,
            const float* __restrict__ born,
            const float* __restrict__ die,
            const float* __restrict__ sf,
            float* __restrict__ ws) {
    const int a = blockIdx.x * 256 + threadIdx.x;    // global atom id
    const float4* e4 = (const float4*)(embs + (size_t)a * NC);

    float si = 0.f, sj = 0.f, ad = 0.f, R = 0.f;
    #pragma unroll
    for (int c = 0; c < NC / 4; ++c) {
        float4 ev = e4[c];
        si = fmaf(ev.x, sf[4 * c + 0], fmaf(ev.y, sf[4 * c + 1],
             fmaf(ev.z, sf[4 * c + 2], fmaf(ev.w, sf[4 * c + 3], si))));
        sj = fmaf(ev.x, sf[NC + 4 * c + 0], fmaf(ev.y, sf[NC + 4 * c + 1],
             fmaf(ev.z, sf[NC + 4 * c + 2], fmaf(ev.w, sf[NC + 4 * c + 3], sj))));
        ad = fmaf(ev.x, die[4 * c + 0], fmaf(ev.y, die[4 * c + 1],
             fmaf(ev.z, die[4 * c + 2], fmaf(ev.w, die[4 * c + 3], ad))));
        R  = fmaf(ev.x, born[4 * c + 0], fmaf(ev.y, born[4 * c + 1],
             fmaf(ev.z, born[4 * c + 2], fmaf(ev.w, born[4 * c + 3], R))));
    }
    float x = X[a * 3 + 0];
    float y = X[a * 3 + 1];
    float z = X[a * 3 + 2];
    float4* Pi = (float4*)(ws + WS_PI);
    float4* Pj = (float4*)(ws + WS_PJ);
    Pi[a] = make_float4(x, y, z, si);
    Pj[a] = make_float4(x, y, z, sj);

    ad += 1e-6f;
    R  += 1.0f;
    float eself = -(1.0f - __builtin_amdgcn_rcpf(ad)) * qs[a]
                  * __builtin_amdgcn_rcpf(R + 1e-6f);

    // block reduction -> private self slot
    #pragma unroll
    for (int off = 32; off > 0; off >>= 1)
        eself += __shfl_down(eself, off, 64);
    __shared__ float wsum[4];
    int lane = threadIdx.x & 63;
    int w = threadIdx.x >> 6;
    if (lane == 0) wsum[w] = eself;
    __syncthreads();
    if (threadIdx.x == 0)
        ws[WS_SELF + blockIdx.x] = wsum[0] + wsum[1] + wsum[2] + wsum[3];
}

// Pass 2: N^2 pair energy with precomputed packed atom data.
__global__ void __launch_bounds__(IT)
pair_kernel(const float* __restrict__ wsc,
            float* __restrict__ ws) {
    const int b  = blockIdx.z;
    const int t  = threadIdx.x;
    const int i0 = b * NA + blockIdx.y * ITILE;
    const int j0 = b * NA + blockIdx.x * JT;

    const float4* Pi = (const float4*)(wsc + WS_PI);
    const float4* Pj = (const float4*)(wsc + WS_PJ);

    __shared__ float4 jd[JT];   // {x, y, z, s_j}
    if (t < JT)
        jd[t] = Pj[j0 + t];

    float4 id[UI];
    #pragma unroll
    for (int u = 0; u < UI; ++u)
        id[u] = Pi[i0 + u * IT + t];
    __syncthreads();

    float acc[UI] = {0.f, 0.f};
    // E_pair ~= rsqrt(d2)*(si+sj) + wd  (wd*N^2 in closed form at finalize)
    #pragma unroll 4
    for (int jj = 0; jj < JT; ++jj) {
        float4 v = jd[jj];
        #pragma unroll
        for (int u = 0; u < UI; ++u) {
            float dx = v.x - id[u].x;
            float dy = v.y - id[u].y;
            float dz = v.z - id[u].z;
            float d2 = fmaf(dx, dx, fmaf(dy, dy, fmaf(dz, dz, 3e-6f)));
            acc[u] = fmaf(__builtin_amdgcn_rsqf(d2), id[u].w + v.w, acc[u]);
        }
    }

    float a = acc[0] + acc[1];
    #pragma unroll
    for (int off = 32; off > 0; off >>= 1)
        a += __shfl_down(a, off, 64);
    __shared__ float wsum[IT / 64];
    int lane = t & 63;
    int w = t >> 6;
    if (lane == 0) wsum[w] = a;
    __syncthreads();
    if (t == 0) {
        int slot = (b * NI + blockIdx.y) * NS + blockIdx.x;
        ws[WS_PAIR + slot] = wsum[0] + wsum[1] + wsum[2] + wsum[3];
    }
}

// Pass 3: one 1024-thread block; batch b owned by waves 4b..4b+3.
__global__ void __launch_bounds__(1024)
finalize_kernel(const float* __restrict__ ws,
                const float* __restrict__ sf,
                float* __restrict__ out) {
    int t = threadIdx.x;
    float v = ws[WS_PAIR + t];
    #pragma unroll
    for (int off = 32; off > 0; off >>= 1)
        v += __shfl_down(v, off, 64);
    __shared__ float wsum[16];
    if ((t & 63) == 0) wsum[t >> 6] = v;
    __syncthreads();
    if (t < NB) {
        float pair = wsum[4 * t] + wsum[4 * t + 1]
                   + wsum[4 * t + 2] + wsum[4 * t + 3];
        float self = 0.f;
        #pragma unroll
        for (int k = 0; k < 8; ++k)
            self += ws[WS_SELF + t * 8 + k];
        float wd = sf[2 * NC];
        float r = CONV001 * 0.5f * (pair + 2.0f * self
                                    + wd * (float)NA * (float)NA);
        out[t] = isnan(r) ? 1e-6f : r;
    }
}

extern "C" void kernel_launch(void* const* d_in, const int* in_sizes, int n_in,
                              void* d_out, int out_size, void* d_ws, size_t ws_size,
                              hipStream_t stream) {
    const float* X    = (const float*)d_in[0];
    const float* embs = (const float*)d_in[1];
    const float* qs   = (const float*)d_in[2];
    // d_in[3] = paired_mask (unused by reference math)
    const float* born = (const float*)d_in[4];
    const float* die  = (const float*)d_in[5];
    const float* sf   = (const float*)d_in[6];
    float* ws  = (float*)d_ws;
    float* out = (float*)d_out;

    atom_kernel<<<NATOM / 256, 256, 0, stream>>>(X, embs, qs, born, die, sf, ws);
    pair_kernel<<<dim3(NS, NI, NB), IT, 0, stream>>>(ws, ws);
    finalize_kernel<<<1, 1024, 0, stream>>>(ws, sf, out);
}